// Round 5
// baseline (1100.054 us; speedup 1.0000x reference)
//
#include <hip/hip_runtime.h>
#include <cmath>

// ---------------------------------------------------------------------------
// Bit-exact replication of the reference's f32 cumsum TREE (JAX/XLA lowers
// jnp.cumsum on non-TPU backends to the TFP associative_scan recursion):
//   L1[i] = x[2i]+x[2i+1]; recurse on L1 -> odd elems;
//   out[0]=x[0]; out[2i+1]=odd[i]; out[2i+2]=odd[i]+x[2i+2].
// Evidence: r1/r4 (exact-f64 phases, different sin/acc precisions) both land
// at 9.155273e-3 (= ref's own f32-scan noise); r2/r3 (faithful fp32
// SEQUENTIAL cumsum) both at 6.01196e-2, orthogonal to the first
// (sqrt(diff) = 5.94e-2 = seq-vs-exact walk) => ref is a log-depth f32 scan.
// Increments / mask / interp replicated with f32 RN ops, no fma, IEEE div.
// Non-chaotic parts (sin of the exact f32 phase, amp blend, k-sum) ~1e-6.
// ---------------------------------------------------------------------------
#pragma clang fp contract(off)

#define SRF   48000.0f
#define NYQF  21600.0f                    // fp32(48000*0.45), exact
constexpr float  TWO_PI_F = 6.283185307179586476925286766559f;  // 0x40C90FDB
constexpr double INV_2PI  = 1.0 / 6.283185307179586476925286766559;

__device__ __forceinline__ float hsin_rev(float r) {  // sin(2*pi*r)
#if __has_builtin(__builtin_amdgcn_sinf)
    return __builtin_amdgcn_sinf(r);                  // v_sin_f32: revolutions
#else
    return __sinf(r * TWO_PI_F);
#endif
}

// kc[b,k] = fp32(k * fp32(sqrt(fp32(1 + fp32(inh*k^2)))))  -- np/jnp-exact
__device__ __forceinline__ float kcval(int k, float ib) {
    float kf = (float)(k + 1);
    float k2 = kf * kf;                   // exact for k<=100
    float m  = ib * k2;                   // RN
    float s1 = 1.0f + m;                  // RN
    float st = (float)sqrt((double)s1);   // == RN-f32 sqrt (53 >= 2*24+2)
    return kf * st;                       // RN
}

// ---- K1: f0_up[b,j], np-exact fp32 linear interp ---------------------------
__global__ void __launch_bounds__(256) k_f0up(const float* __restrict__ f0,
        float* __restrict__ f0up, int T, int n, float pf) {
    int j = blockIdx.x * 256 + threadIdx.x;
    int b = blockIdx.y;
    if (j >= n) return;
    float pos = ((float)j + 0.5f);
    pos = pos * pf;                       // pf = fp32(T/n)
    pos = pos - 0.5f;
    pos = fmaxf(pos, 0.0f);
    pos = fminf(pos, (float)(T - 1));
    int   i0 = (int)pos;
    int   i1 = min(i0 + 1, T - 1);
    float w  = pos - (float)i0;
    float omw = 1.0f - w;
    const float* fb = f0 + b * T;
    f0up[(size_t)b * n + j] = fb[i0] * omw + fb[i1] * w;   // no fma
}

// ---- K2: one block per (b,k) chain: bit-exact tree scan + synth emit -------
__global__ void __launch_bounds__(256) k_scan_synth(
        const float* __restrict__ harm, const float* __restrict__ f0up,
        const float* __restrict__ inh,  float* __restrict__ out,
        int B, int T, int N, int n, float pf) {
    extern __shared__ float lv[];         // levels 2..P, n/2 floats is enough
    const int k   = blockIdx.x;
    const int b   = blockIdx.y;
    const int tid = threadIdx.x;
    const float kc = kcval(k, inh[b]);
    const float* fb = f0up + (size_t)b * n;

    // increment j: fp32( fp32( 2pi_f32 * fp32(kc*f0up_j) ) / 48000 ), IEEE div
    auto inc = [&](int j) -> float {
        float u    = fb[j];
        float inst = kc * u;
        float tt   = TWO_PI_F * inst;
        return tt / SRF;
    };

    // level geometry: len[l] = floor(len[l-1]/2), len[1] = n/2 (n even)
    int len[24], off[24];
    len[1] = n >> 1;
    int P = 1;
    for (int l = 2; l < 24; ++l) {
        len[l] = len[l - 1] >> 1;
        P = l;
        if (len[l] == 1) break;
    }
    off[2] = 0;
    for (int l = 3; l <= P; ++l) off[l] = off[l - 1] + len[l - 1];

    // ---- upsweep: L2 straight from increments (L1 recomputed on the fly) ---
    {
        const float4* f4 = (const float4*)fb;     // b*n*4 % 16 == 0
        float* L2 = lv + off[2];
        for (int i = tid; i < len[2]; i += 256) {
            float4 u = f4[i];
            float a0 = (TWO_PI_F * (kc * u.x)) / SRF;
            float a1 = (TWO_PI_F * (kc * u.y)) / SRF;
            float a2 = (TWO_PI_F * (kc * u.z)) / SRF;
            float a3 = (TWO_PI_F * (kc * u.w)) / SRF;
            L2[i] = (a0 + a1) + (a2 + a3);        // L1[2i]+L1[2i+1]
        }
    }
    __syncthreads();
    for (int l = 3; l <= P; ++l) {
        const float* src = lv + off[l - 1];
        float*       dst = lv + off[l];
        for (int i = tid; i < len[l]; i += 256)
            dst[i] = src[2 * i] + src[2 * i + 1];
        __syncthreads();
    }

    // ---- downsweep in place: scan_l[2i+1]=scan_{l+1}[i];
    //      scan_l[2i+2]=scan_{l+1}[i]+L_l[2i+2]; scan_l[0]=L_l[0] -----------
    for (int l = P - 1; l >= 2; --l) {
        float*       arr = lv + off[l];
        const float* hi  = lv + off[l + 1];
        for (int i = tid; i < len[l + 1]; i += 256) {
            float v = hi[i];
            int e = 2 * i + 2;
            if (e < len[l]) arr[e] = v + arr[e];
            arr[2 * i + 1] = v;
        }
        __syncthreads();
    }
    const float* scan2 = lv + off[2];

    // ---- emit: phase(j) from scan2 + <=3 recomputed increments -------------
    const float  tmaxf = (float)(T - 1);
    const float  invN  = 1.0f / (float)N;
    const float* hb    = harm + (size_t)b * T * N + k;
    float*       ob    = out + (size_t)b * n;

    auto emit = [&](int j, float ph) {
        float u    = fb[j];
        float inst = kc * u;                     // same RN product as ref mask
        if (!(inst < NYQF)) return;              // nyq_mask
        double pr = (double)ph * INV_2PI;        // exact mod-2pi of f32 phase
        double fr = pr - rint(pr);               // [-0.5, 0.5] revolutions
        float  sv = hsin_rev((float)fr);
        float pos = ((float)j + 0.5f);
        pos = pos * pf;
        pos = pos - 0.5f;
        pos = fmaxf(pos, 0.0f);
        pos = fminf(pos, tmaxf);
        int   i0 = (int)pos;
        int   i1 = min(i0 + 1, T - 1);
        float w  = pos - (float)i0;
        float a  = hb[(size_t)i0 * N] * (1.0f - w) + hb[(size_t)i1 * N] * w;
        atomicAdd(&ob[j], (a * sv) * invN);
    };

    if (tid == 0) emit(0, inc(0));               // out[0] = x[0]
    const int H = n >> 1;                        // scan1 index range
    for (int t = tid; t < H; t += 256) {
        float s1;                                // scan1[t]
        if (t == 0)      s1 = inc(0) + inc(1);                      // L1[0]
        else if (t & 1)  s1 = scan2[(t - 1) >> 1];
        else             s1 = scan2[(t >> 1) - 1] + (inc(2 * t) + inc(2 * t + 1));
        emit(2 * t + 1, s1);                     // out[2t+1] = scan1[t]
        int je = 2 * t + 2;
        if (je < n) emit(je, s1 + inc(je));      // out[2t+2] = scan1[t]+x[2t+2]
    }
}

extern "C" void kernel_launch(void* const* d_in, const int* in_sizes, int n_in,
                              void* d_out, int out_size, void* d_ws, size_t ws_size,
                              hipStream_t stream) {
    const int B = in_sizes[2];                 // 16
    const int T = in_sizes[1] / B;             // 250
    const int N = in_sizes[0] / (B * T);       // 100
    const int n = out_size / B;                // 48000 (even)
    const float pf = (float)((double)T / (double)n);

    const float* harm = (const float*)d_in[0];
    const float* f0   = (const float*)d_in[1];
    const float* inh  = (const float*)d_in[2];
    float* out = (float*)d_out;
    float* f0up = (float*)d_ws;                // B*n floats = 3.07 MB

    hipMemsetAsync(d_out, 0, (size_t)out_size * sizeof(float), stream);

    k_f0up<<<dim3((n + 255) / 256, B), 256, 0, stream>>>(f0, f0up, T, n, pf);

    const size_t lds_bytes = (size_t)(n / 2) * sizeof(float);  // 96 KB
    k_scan_synth<<<dim3(N, B), 256, lds_bytes, stream>>>(
        harm, f0up, inh, out, B, T, N, n, pf);
}

// Round 6
// 261.223 us; speedup vs baseline: 4.2112x; 4.2112x over previous
//
#include <hip/hip_runtime.h>
#include <cmath>

// ---------------------------------------------------------------------------
// Bit-exact replication of the reference's f32 cumsum TREE (JAX associative
// scan), verified in round 5 (absmax 1.83e-3, PASS). This round: same math,
// new schedule. Round-5 counters: VALUBusy 13%, Occ 10.8% (96KB LDS -> 1
// block/CU), WRITE_SIZE 447 MB (54M cross-block atomicAdds, 149x ideal).
// Fix: (1) k_scan4 stores the level-4 scan (3000 f32/chain) to ws with only
// 24 KB LDS; (2) k_synth2 tiles j, loops k INSIDE the block, reconstructs
// phases from scan4 + shared increments, accumulates in registers -> zero
// atomics, one coalesced store per output. Fallback to the proven round-5
// kernel if ws_size < 22.3 MB.
// ---------------------------------------------------------------------------
#pragma clang fp contract(off)

#define SRF   48000.0f
#define NYQF  21600.0f                    // fp32(48000*0.45), exact
constexpr float  TWO_PI_F = 6.283185307179586476925286766559f;  // 0x40C90FDB
constexpr double INV_2PI  = 1.0 / 6.283185307179586476925286766559;

__device__ __forceinline__ float hsin_rev(float r) {  // sin(2*pi*r)
#if __has_builtin(__builtin_amdgcn_sinf)
    return __builtin_amdgcn_sinf(r);                  // v_sin_f32: revolutions
#else
    return __sinf(r * TWO_PI_F);
#endif
}

// kc[b,k] = fp32(k * fp32(sqrt(fp32(1 + fp32(inh*k^2)))))  -- np/jnp-exact
__device__ __forceinline__ float kcval(int k, float ib) {
    float kf = (float)(k + 1);
    float k2 = kf * kf;                   // exact for k<=100
    float m  = ib * k2;                   // RN
    float s1 = 1.0f + m;                  // RN
    float st = (float)sqrt((double)s1);   // == RN-f32 sqrt (53 >= 2*24+2)
    return kf * st;                       // RN
}

// ---- K1: f0_up[b,j], np-exact fp32 linear interp ---------------------------
__global__ void __launch_bounds__(256) k_f0up(const float* __restrict__ f0,
        float* __restrict__ f0up, int T, int n, float pf) {
    int j = blockIdx.x * 256 + threadIdx.x;
    int b = blockIdx.y;
    if (j >= n) return;
    float pos = ((float)j + 0.5f);
    pos = pos * pf;
    pos = pos - 0.5f;
    pos = fmaxf(pos, 0.0f);
    pos = fminf(pos, (float)(T - 1));
    int   i0 = (int)pos;
    int   i1 = min(i0 + 1, T - 1);
    float w  = pos - (float)i0;
    float omw = 1.0f - w;
    const float* fb = f0 + b * T;
    f0up[(size_t)b * n + j] = fb[i0] * omw + fb[i1] * w;
}

// ---- K2a: per (b,k) produce scan4 (level-4 inclusive tree scan) ------------
// L4[i] built straight from 16 increments with round-5's exact association:
// ((a0+a1)+(a2+a3)) + ((a4+a5)+(a6+a7))  pairs up through L2,L3,L4.
__global__ void __launch_bounds__(256) k_scan4(const float* __restrict__ f0up,
        const float* __restrict__ inh, float* __restrict__ scan4,
        int N, int n) {
    __shared__ float lv[6016];            // levels 4..P for len4 = n/16 = 3000
    const int k   = blockIdx.x;
    const int b   = blockIdx.y;
    const int tid = threadIdx.x;
    const float kc = kcval(k, inh[b]);
    const float4* f4 = (const float4*)(f0up + (size_t)b * n);

    int len[28], off[28];
    len[4] = n >> 4;
    int P = 4;
    for (int l = 5; l < 28; ++l) { len[l] = len[l-1] >> 1; P = l; if (len[l] == 1) break; }
    off[4] = 0;
    for (int l = 5; l <= P; ++l) off[l] = off[l-1] + len[l-1];

    for (int i = tid; i < len[4]; i += 256) {
        float4 u0 = f4[4*i], u1 = f4[4*i+1], u2 = f4[4*i+2], u3 = f4[4*i+3];
        float a0=(TWO_PI_F*(kc*u0.x))/SRF, a1=(TWO_PI_F*(kc*u0.y))/SRF;
        float a2=(TWO_PI_F*(kc*u0.z))/SRF, a3=(TWO_PI_F*(kc*u0.w))/SRF;
        float a4=(TWO_PI_F*(kc*u1.x))/SRF, a5=(TWO_PI_F*(kc*u1.y))/SRF;
        float a6=(TWO_PI_F*(kc*u1.z))/SRF, a7=(TWO_PI_F*(kc*u1.w))/SRF;
        float a8=(TWO_PI_F*(kc*u2.x))/SRF, a9=(TWO_PI_F*(kc*u2.y))/SRF;
        float aA=(TWO_PI_F*(kc*u2.z))/SRF, aB=(TWO_PI_F*(kc*u2.w))/SRF;
        float aC=(TWO_PI_F*(kc*u3.x))/SRF, aD=(TWO_PI_F*(kc*u3.y))/SRF;
        float aE=(TWO_PI_F*(kc*u3.z))/SRF, aF=(TWO_PI_F*(kc*u3.w))/SRF;
        float L2a=(a0+a1)+(a2+a3), L2b=(a4+a5)+(a6+a7);
        float L2c=(a8+a9)+(aA+aB), L2d=(aC+aD)+(aE+aF);
        lv[i] = (L2a+L2b) + (L2c+L2d);    // L4[i] = L3[2i]+L3[2i+1]
    }
    __syncthreads();
    for (int l = 5; l <= P; ++l) {
        const float* src = lv + off[l-1];
        float*       dst = lv + off[l];
        for (int i = tid; i < len[l]; i += 256) dst[i] = src[2*i] + src[2*i+1];
        __syncthreads();
    }
    for (int l = P - 1; l >= 4; --l) {    // downsweep (round-5 formulas)
        float*       arr = lv + off[l];
        const float* hi  = lv + off[l+1];
        for (int i = tid; i < len[l+1]; i += 256) {
            float v = hi[i];
            int e = 2*i + 2;
            if (e < len[l]) arr[e] = v + arr[e];
            arr[2*i + 1] = v;
        }
        __syncthreads();
    }
    float* sp = scan4 + (size_t)(b * N + k) * len[4];
    for (int i = tid; i < len[4]; i += 256) sp[i] = lv[i];
}

// ---- K2b: j-tile synth, k-loop inside block, register accumulation ---------
__global__ void __launch_bounds__(256) k_synth2(
        const float* __restrict__ harm, const float* __restrict__ f0up,
        const float* __restrict__ inh,  const float* __restrict__ scan4,
        float* __restrict__ out, int B, int T, int N, int n, float pf) {
    const int t0  = blockIdx.x * 256;
    const int b   = blockIdx.y;
    const int tid = threadIdx.x;
    const int H   = n >> 1;
    const int t   = t0 + tid;
    const bool valid = t < H;
    const int jl0 = 2*t0 - 16;            // staged j range [jl0, jl0+544)
    const int L4len = n >> 4;

    __shared__ float us[544];             // f0up window (+halo)
    __shared__ float incs[544];           // per-k increments
    __shared__ float amps[5][128];        // 5 amp rows x k
    __shared__ float kcs[128];
    __shared__ float red[256];

    const float ib = inh[b];
    for (int idx = tid; idx < 544; idx += 256) {
        int j = jl0 + idx;
        us[idx] = (j >= 0 && j < n) ? f0up[(size_t)b * n + j] : __builtin_inff();
    }
    if (tid < N) kcs[tid] = kcval(tid, ib);

    // block-wide umin (conservative over staged superset)
    float um = __builtin_inff();
    __syncthreads();
    for (int idx = tid; idx < 544; idx += 256) um = fminf(um, us[idx]);
    red[tid] = um;
    __syncthreads();
    for (int s = 128; s > 0; s >>= 1) {
        if (tid < s) red[tid] = fminf(red[tid], red[tid + s]);
        __syncthreads();
    }
    const float umin = red[0];

    const float tmaxf = (float)(T - 1);
    auto posOf = [&](int j) -> float {
        float p = ((float)j + 0.5f);
        p = p * pf; p = p - 0.5f;
        p = fmaxf(p, 0.0f); return fminf(p, tmaxf);
    };
    const int i0min = (int)posOf(2*t0 + 1);
    for (int idx = tid; idx < 5 * N; idx += 256) {
        int r = idx / N, kk = idx - r * N;
        int row = min(i0min + r, T - 1);
        amps[r][kk] = harm[((size_t)b * T + row) * N + kk];
    }
    __syncthreads();

    // per-thread reconstruction plan (parity cases of round-5 downsweep)
    int c1, i2 = 0, c2 = 0, m3 = 0, c3 = 0, s4i = 0;
    int idxA = 0, idxL2 = 0, idxL3 = 0;
    if (t == 0) c1 = 0;
    else if (t & 1) { c1 = 1; i2 = (t - 1) >> 1; }
    else { c1 = 2; i2 = (t >> 1) - 1; idxA = 2*tid + 16; }
    if (c1 != 0) {
        if (i2 == 0) c2 = 0;
        else if (i2 & 1) { c2 = 1; m3 = (i2 - 1) >> 1; }
        else { c2 = 2; m3 = (i2 >> 1) - 1; idxL2 = 4*i2 - jl0; }
        if (c2 != 0) {
            if (m3 == 0) c3 = 0;
            else if (m3 & 1) { c3 = 1; s4i = (m3 - 1) >> 1; }
            else { c3 = 2; s4i = (m3 >> 1) - 1; idxL3 = 8*m3 - jl0; }
        }
    }
    const int idxJ1 = 2*tid + 17;         // j = 2t+1
    const int idxJ2 = 2*tid + 18;         // j = 2t+2
    const float u1 = us[idxJ1];
    const float u2 = us[idxJ2];
    const int z = -jl0;                   // LDS index of j==0 (tile 0 only)

    float p1 = posOf(2*t + 1), p2 = posOf(2*t + 2), p0 = posOf(0);
    int i01 = (int)p1, i02 = (int)p2, i00 = (int)p0;
    float w1 = p1 - (float)i01, w2 = p2 - (float)i02, w0 = p0 - (float)i00;
    int ra1 = i01 - i0min, rb1 = min(i01 + 1, T - 1) - i0min;
    int ra2 = i02 - i0min, rb2 = min(i02 + 1, T - 1) - i0min;
    int ra0 = max(i00 - i0min, 0), rb0 = max(min(i00 + 1, T - 1) - i0min, 0);

    float acc1 = 0.0f, acc2 = 0.0f, acc0 = 0.0f;
    const size_t s4base = (size_t)(b * N) * L4len;

    for (int k = 0; k < N; ++k) {
        const float kc = kcs[k];
        if (kc * umin >= NYQF) break;     // kc monotone in k; block-uniform
        __syncthreads();                  // prev-iter incs reads complete
        for (int idx = tid; idx < 544; idx += 256)
            incs[idx] = (TWO_PI_F * (kc * us[idx])) / SRF;
        __syncthreads();

        if (valid) {
            const float* s4p = scan4 + s4base + (size_t)k * L4len;
            float s3v = 0.0f, s2v = 0.0f, s1v;
            if (c1 != 0 && c2 != 0) {
                if (c3 == 0) {
                    float b0 = (incs[z]+incs[z+1]) + (incs[z+2]+incs[z+3]);
                    float b1 = (incs[z+4]+incs[z+5]) + (incs[z+6]+incs[z+7]);
                    s3v = b0 + b1;                    // L3[0]
                } else {
                    float g = s4p[s4i];
                    if (c3 == 1) s3v = g;
                    else {
                        float b0 = (incs[idxL3]+incs[idxL3+1]) + (incs[idxL3+2]+incs[idxL3+3]);
                        float b1 = (incs[idxL3+4]+incs[idxL3+5]) + (incs[idxL3+6]+incs[idxL3+7]);
                        s3v = g + (b0 + b1);          // scan3 even
                    }
                }
            }
            if (c1 != 0) {
                if (c2 == 0) s2v = (incs[z]+incs[z+1]) + (incs[z+2]+incs[z+3]); // L2[0]
                else if (c2 == 1) s2v = s3v;
                else s2v = s3v + ((incs[idxL2]+incs[idxL2+1]) + (incs[idxL2+2]+incs[idxL2+3]));
            }
            if (c1 == 0)      s1v = incs[z] + incs[z+1];           // L1[0]
            else if (c1 == 1) s1v = s2v;
            else              s1v = s2v + (incs[idxA] + incs[idxA+1]);

            float inst1 = kc * u1;
            if (inst1 < NYQF) {
                double pr = (double)s1v * INV_2PI;
                double fr = pr - rint(pr);
                float  sv = hsin_rev((float)fr);
                float  a  = amps[ra1][k] * (1.0f - w1) + amps[rb1][k] * w1;
                acc1 += a * sv;
            }
            if (2*t + 2 < n) {
                float inst2 = kc * u2;
                if (inst2 < NYQF) {
                    float ph2 = s1v + incs[idxJ2];
                    double pr = (double)ph2 * INV_2PI;
                    double fr = pr - rint(pr);
                    float  sv = hsin_rev((float)fr);
                    float  a  = amps[ra2][k] * (1.0f - w2) + amps[rb2][k] * w2;
                    acc2 += a * sv;
                }
            }
            if (c1 == 0) {                 // j = 0: out[0] = x[0]
                float inst0 = kc * us[z];
                if (inst0 < NYQF) {
                    double pr = (double)incs[z] * INV_2PI;
                    double fr = pr - rint(pr);
                    float  sv = hsin_rev((float)fr);
                    float  a  = amps[ra0][k] * (1.0f - w0) + amps[rb0][k] * w0;
                    acc0 += a * sv;
                }
            }
        }
    }

    const float Nf = (float)N;
    float* ob = out + (size_t)b * n;
    if (valid) {
        ob[2*t + 1] = acc1 / Nf;
        if (2*t + 2 < n) ob[2*t + 2] = acc2 / Nf;
        if (c1 == 0) ob[0] = acc0 / Nf;
    }
}

// ---- Fallback: round-5 proven kernel (atomics, 96 KB LDS) ------------------
__global__ void __launch_bounds__(256) k_scan_synth(
        const float* __restrict__ harm, const float* __restrict__ f0up,
        const float* __restrict__ inh,  float* __restrict__ out,
        int B, int T, int N, int n, float pf) {
    extern __shared__ float lv[];
    const int k   = blockIdx.x;
    const int b   = blockIdx.y;
    const int tid = threadIdx.x;
    const float kc = kcval(k, inh[b]);
    const float* fb = f0up + (size_t)b * n;

    auto inc = [&](int j) -> float {
        float u    = fb[j];
        float inst = kc * u;
        float tt   = TWO_PI_F * inst;
        return tt / SRF;
    };

    int len[24], off[24];
    len[1] = n >> 1;
    int P = 1;
    for (int l = 2; l < 24; ++l) { len[l] = len[l-1] >> 1; P = l; if (len[l] == 1) break; }
    off[2] = 0;
    for (int l = 3; l <= P; ++l) off[l] = off[l-1] + len[l-1];

    {
        const float4* f4 = (const float4*)fb;
        float* L2 = lv + off[2];
        for (int i = tid; i < len[2]; i += 256) {
            float4 u = f4[i];
            float a0 = (TWO_PI_F * (kc * u.x)) / SRF;
            float a1 = (TWO_PI_F * (kc * u.y)) / SRF;
            float a2 = (TWO_PI_F * (kc * u.z)) / SRF;
            float a3 = (TWO_PI_F * (kc * u.w)) / SRF;
            L2[i] = (a0 + a1) + (a2 + a3);
        }
    }
    __syncthreads();
    for (int l = 3; l <= P; ++l) {
        const float* src = lv + off[l-1];
        float*       dst = lv + off[l];
        for (int i = tid; i < len[l]; i += 256) dst[i] = src[2*i] + src[2*i+1];
        __syncthreads();
    }
    for (int l = P - 1; l >= 2; --l) {
        float*       arr = lv + off[l];
        const float* hi  = lv + off[l+1];
        for (int i = tid; i < len[l+1]; i += 256) {
            float v = hi[i];
            int e = 2*i + 2;
            if (e < len[l]) arr[e] = v + arr[e];
            arr[2*i + 1] = v;
        }
        __syncthreads();
    }
    const float* scan2 = lv + off[2];

    const float  tmaxf = (float)(T - 1);
    const float  invN  = 1.0f / (float)N;
    const float* hb    = harm + (size_t)b * T * N + k;
    float*       ob    = out + (size_t)b * n;

    auto emit = [&](int j, float ph) {
        float u    = fb[j];
        float inst = kc * u;
        if (!(inst < NYQF)) return;
        double pr = (double)ph * INV_2PI;
        double fr = pr - rint(pr);
        float  sv = hsin_rev((float)fr);
        float pos = ((float)j + 0.5f);
        pos = pos * pf; pos = pos - 0.5f;
        pos = fmaxf(pos, 0.0f); pos = fminf(pos, tmaxf);
        int   i0 = (int)pos;
        int   i1 = min(i0 + 1, T - 1);
        float w  = pos - (float)i0;
        float a  = hb[(size_t)i0 * N] * (1.0f - w) + hb[(size_t)i1 * N] * w;
        atomicAdd(&ob[j], (a * sv) * invN);
    };

    if (tid == 0) emit(0, inc(0));
    const int Hh = n >> 1;
    for (int tt = tid; tt < Hh; tt += 256) {
        float s1;
        if (tt == 0)      s1 = inc(0) + inc(1);
        else if (tt & 1)  s1 = scan2[(tt - 1) >> 1];
        else              s1 = scan2[(tt >> 1) - 1] + (inc(2*tt) + inc(2*tt + 1));
        emit(2*tt + 1, s1);
        int je = 2*tt + 2;
        if (je < n) emit(je, s1 + inc(je));
    }
}

extern "C" void kernel_launch(void* const* d_in, const int* in_sizes, int n_in,
                              void* d_out, int out_size, void* d_ws, size_t ws_size,
                              hipStream_t stream) {
    const int B = in_sizes[2];                 // 16
    const int T = in_sizes[1] / B;             // 250
    const int N = in_sizes[0] / (B * T);       // 100
    const int n = out_size / B;                // 48000
    const float pf = (float)((double)T / (double)n);

    const float* harm = (const float*)d_in[0];
    const float* f0   = (const float*)d_in[1];
    const float* inh  = (const float*)d_in[2];
    float* out  = (float*)d_out;
    float* f0up = (float*)d_ws;                // B*n floats = 3.07 MB

    const size_t needFast = (size_t)B * n * 4 + (size_t)B * N * (n / 16) * 4;
    const bool fast = (ws_size >= needFast) && (n % 16 == 0) && (N <= 128);

    k_f0up<<<dim3((n + 255) / 256, B), 256, 0, stream>>>(f0, f0up, T, n, pf);

    if (fast) {
        float* scan4 = (float*)((char*)d_ws + (size_t)B * n * 4);
        k_scan4<<<dim3(N, B), 256, 0, stream>>>(f0up, inh, scan4, N, n);
        const int tiles = (n / 2 + 255) / 256;             // 94
        k_synth2<<<dim3(tiles, B), 256, 0, stream>>>(
            harm, f0up, inh, scan4, out, B, T, N, n, pf);
    } else {
        hipMemsetAsync(d_out, 0, (size_t)out_size * sizeof(float), stream);
        const size_t lds_bytes = (size_t)(n / 2) * sizeof(float);  // 96 KB
        k_scan_synth<<<dim3(N, B), 256, lds_bytes, stream>>>(
            harm, f0up, inh, out, B, T, N, n, pf);
    }
}